// Round 3
// baseline (1361.258 us; speedup 1.0000x reference)
//
#include <hip/hip_runtime.h>
#include <math.h>

#define TPB 256
#define DIM 128            // K
#define NCODES 1024        // N
#define M_ROWS (32*64*64)  // 131072 rows

// fl32(v*v) with no possibility of FMA contraction into a later add:
// the f64 product is exact (24-bit^2 <= 53 bits), single rounding on cast.
__device__ __forceinline__ float sqf(float v) {
    return (float)((double)v * (double)v);
}

// ---------------------------------------------------------------------------
// Prep: cbT[n][k] transpose of codebook; cc[n] = numpy-style axis-0 sum:
// sequential over k of individually-rounded squares.
// ---------------------------------------------------------------------------
__global__ void vq_prep(const float* __restrict__ cb,
                        float* __restrict__ cbT,
                        float* __restrict__ cc) {
    int n = blockIdx.x * blockDim.x + threadIdx.x;
    if (n >= NCODES) return;
    float acc = 0.f;
    for (int k = 0; k < DIM; ++k) {
        float v = cb[k * NCODES + n];   // coalesced across n
        cbT[n * DIM + k] = v;
        acc = acc + sqf(v);             // sequential, np axis-0 reduce order
    }
    cc[n] = acc;
}

// ---------------------------------------------------------------------------
// Main: thread-per-row. Replicates numpy fp32 semantics exactly:
//   xx   : pairwise sum, 8 scalar accumulators, block n=128
//   sim  : k-sequential fp32 FMA chain (BLAS sgemm micro-kernel order)
//   dist : fl(fl(xx + cc_n) - 2*sim_n); argmin = first strict min
//   out  : fl(x + fl(q - x))
// Codebook access is wave-uniform -> scalar (s_load) reads; x row in VGPRs.
// ---------------------------------------------------------------------------
__global__ __launch_bounds__(TPB, 2) void vq_main(const float* __restrict__ x,
                                                  const float* __restrict__ cbT,
                                                  const float* __restrict__ cc,
                                                  float* __restrict__ out) {
    __shared__ int sidx[TPB];

    const int t   = threadIdx.x;
    const int row = blockIdx.x * TPB + t;

    const float4* x4 = (const float4*)x;
    float4 xr[32];
#pragma unroll
    for (int j = 0; j < 32; ++j) xr[j] = x4[(size_t)row * 32 + j];

    // ---- xx: numpy pairwise_sum, n=128 block, 8 accumulators ----
    float r0 = sqf(xr[0].x), r1 = sqf(xr[0].y), r2 = sqf(xr[0].z), r3 = sqf(xr[0].w);
    float r4 = sqf(xr[1].x), r5 = sqf(xr[1].y), r6 = sqf(xr[1].z), r7 = sqf(xr[1].w);
#pragma unroll
    for (int i = 2; i < 32; i += 2) {
        r0 = r0 + sqf(xr[i].x);     r1 = r1 + sqf(xr[i].y);
        r2 = r2 + sqf(xr[i].z);     r3 = r3 + sqf(xr[i].w);
        r4 = r4 + sqf(xr[i + 1].x); r5 = r5 + sqf(xr[i + 1].y);
        r6 = r6 + sqf(xr[i + 1].z); r7 = r7 + sqf(xr[i + 1].w);
    }
    const float xx = ((r0 + r1) + (r2 + r3)) + ((r4 + r5) + (r6 + r7));

    float smin = INFINITY;
    int   imin = 0;

    for (int n0 = 0; n0 < NCODES; n0 += 8) {
        const float* c0 = cbT + (size_t)(n0 + 0) * DIM;
        const float* c1 = cbT + (size_t)(n0 + 1) * DIM;
        const float* c2 = cbT + (size_t)(n0 + 2) * DIM;
        const float* c3 = cbT + (size_t)(n0 + 3) * DIM;
        const float* c4 = cbT + (size_t)(n0 + 4) * DIM;
        const float* c5 = cbT + (size_t)(n0 + 5) * DIM;
        const float* c6 = cbT + (size_t)(n0 + 6) * DIM;
        const float* c7 = cbT + (size_t)(n0 + 7) * DIM;

        float a0 = 0.f, a1 = 0.f, a2 = 0.f, a3 = 0.f;
        float a4 = 0.f, a5 = 0.f, a6 = 0.f, a7 = 0.f;

        // 8 independent k-sequential FMA chains (k ascending within each chain).
#define FMA8(comp, kidx)                       \
        a0 = fmaf(c0[kidx], xv.comp, a0);      \
        a1 = fmaf(c1[kidx], xv.comp, a1);      \
        a2 = fmaf(c2[kidx], xv.comp, a2);      \
        a3 = fmaf(c3[kidx], xv.comp, a3);      \
        a4 = fmaf(c4[kidx], xv.comp, a4);      \
        a5 = fmaf(c5[kidx], xv.comp, a5);      \
        a6 = fmaf(c6[kidx], xv.comp, a6);      \
        a7 = fmaf(c7[kidx], xv.comp, a7);

#pragma unroll
        for (int k4 = 0; k4 < 32; ++k4) {
            const float4 xv = xr[k4];
            const int kb = k4 * 4;
            FMA8(x, kb + 0)
            FMA8(y, kb + 1)
            FMA8(z, kb + 2)
            FMA8(w, kb + 3)
        }
#undef FMA8

        // np dist + first-min, ascending n. 2*sim is exact (a+a).
#define STEP(c)                                              \
        {                                                    \
            float tt = xx + cc[n0 + c];                      \
            float d  = tt - (a##c + a##c);                   \
            if (d < smin) { smin = d; imin = n0 + c; }       \
        }
        STEP(0) STEP(1) STEP(2) STEP(3) STEP(4) STEP(5) STEP(6) STEP(7)
#undef STEP
    }

    sidx[t] = imin;
    __syncthreads();

    // Coalesced epilogue: out = fl(x + fl(q - x)), q = codebook column imin.
    const float4* cbT4 = (const float4*)cbT;
    float4* out4 = (float4*)out;
    const size_t obase = (size_t)blockIdx.x * TPB * 32;
#pragma unroll
    for (int it = 0; it < 32; ++it) {
        int e  = t + it * TPB;     // 0..8191
        int rl = e >> 5;           // local row
        int k4 = e & 31;
        float4 q  = cbT4[(size_t)sidx[rl] * 32 + k4];
        float4 xv = x4[obase + e];
        float4 o;
        o.x = xv.x + (q.x - xv.x);
        o.y = xv.y + (q.y - xv.y);
        o.z = xv.z + (q.z - xv.z);
        o.w = xv.w + (q.w - xv.w);
        out4[obase + e] = o;
    }
}

// ---------------------------------------------------------------------------
extern "C" void kernel_launch(void* const* d_in, const int* in_sizes, int n_in,
                              void* d_out, int out_size, void* d_ws, size_t ws_size,
                              hipStream_t stream) {
    const float* x  = (const float*)d_in[0];   // [32,64,64,128] fp32
    const float* cb = (const float*)d_in[1];   // [128,1024] fp32
    float* out = (float*)d_out;                // [32,64,64,128] fp32

    // Workspace: cbT [1024*128] f32 | cc [1024] f32
    float* cbT = (float*)d_ws;
    float* cc  = cbT + NCODES * DIM;

    vq_prep<<<(NCODES + TPB - 1) / TPB, TPB, 0, stream>>>(cb, cbT, cc);
    vq_main<<<M_ROWS / TPB, TPB, 0, stream>>>(x, cbT, cc, out);
}

// Round 4
// 259.527 us; speedup vs baseline: 5.2452x; 5.2452x over previous
//
#include <hip/hip_runtime.h>
#include <math.h>

typedef _Float16 half8 __attribute__((ext_vector_type(8)));
typedef float    f32x4 __attribute__((ext_vector_type(4)));

#define DIM     128
#define NCODES  1024
#define M_ROWS  (32*64*64)   // 131072
#define MTILE   128          // rows per block in phase 1
#define NCHUNK  64           // codes per LDS chunk in phase 1
#define BSTRIDE 136          // halves per padded LDS row (16B aligned, conflict-benign)
#define M_TEST  3.0e-3f      // flag margin (quantized-score gap)
#define WL_CAP  16384

// fl32(v*v), immune to FMA contraction (f64 product exact, one rounding).
__device__ __forceinline__ float sqf(float v) {
    return (float)((double)v * (double)v);
}

// ---------------------------------------------------------------------------
// Prep: cbT[n][k] (f32 transpose, for phase-3 gather), ch[n][k] (fp16, GEMM B),
// cc[n] = np axis-0 sum of rounded squares (sequential k). Zero worklist cnt.
// ---------------------------------------------------------------------------
__global__ void vq_prep(const float* __restrict__ cb,
                        float* __restrict__ cbT,
                        _Float16* __restrict__ ch,
                        float* __restrict__ cc,
                        int* __restrict__ cnt) {
    if (blockIdx.x == 0 && threadIdx.x == 0) *cnt = 0;
    int n = blockIdx.x * blockDim.x + threadIdx.x;
    if (n >= NCODES) return;
    float acc = 0.f;
    for (int k = 0; k < DIM; ++k) {
        float v = cb[k * NCODES + n];       // coalesced across n
        cbT[n * DIM + k] = v;
        ch[n * DIM + k]  = (_Float16)v;
        acc = acc + sqf(v);                 // np axis-0 order
    }
    cc[n] = acc;
}

// ---------------------------------------------------------------------------
// Phase 1: fp16 MFMA scoring, fused top-2 argmin.
// Block: 256 thr (4 waves), 128 rows; wave w -> rows [w*32, w*32+32).
// Per wave: 2 m-frags x 4 n-frags, K=128 as 4 MFMA k-steps. B chunks via LDS.
// Score s' = (cc[n]+4) - 2*sim, clamped >= 0.25 -> positive => float bit
// pattern is uint-monotone. packed = (bits & ~0x3FF) | col. Top-2 via min/max.
// ---------------------------------------------------------------------------
__global__ __launch_bounds__(256, 2) void vq_gemm(const float* __restrict__ x,
                                                  const _Float16* __restrict__ ch,
                                                  const float* __restrict__ cc,
                                                  int* __restrict__ idx,
                                                  int* __restrict__ cnt,
                                                  int* __restrict__ wl) {
    __shared__ _Float16 bs[NCHUNK * BSTRIDE];

    const int t      = threadIdx.x;
    const int w      = t >> 6;
    const int L      = t & 63;
    const int lane15 = L & 15;
    const int quad   = L >> 4;
    const int rowbase = blockIdx.x * MTILE + w * 32;

    // A fragments direct from global x (f32 -> fp16), persistent across chunks.
    // A[m][k]: m = lane&15, k = kstep*32 + quad*8 + j.
    half8 af[2][4];
#pragma unroll
    for (int m = 0; m < 2; ++m) {
#pragma unroll
        for (int ks = 0; ks < 4; ++ks) {
            const float* src = x + (size_t)(rowbase + m * 16 + lane15) * DIM
                                 + ks * 32 + quad * 8;
            float4 f0 = *(const float4*)src;
            float4 f1 = *(const float4*)(src + 4);
            half8 h;
            h[0] = (_Float16)f0.x; h[1] = (_Float16)f0.y;
            h[2] = (_Float16)f0.z; h[3] = (_Float16)f0.w;
            h[4] = (_Float16)f1.x; h[5] = (_Float16)f1.y;
            h[6] = (_Float16)f1.z; h[7] = (_Float16)f1.w;
            af[m][ks] = h;
        }
    }

    unsigned p1[2][4], p2[2][4];
#pragma unroll
    for (int m = 0; m < 2; ++m)
#pragma unroll
        for (int r = 0; r < 4; ++r) { p1[m][r] = 0xFFFFFFFFu; p2[m][r] = 0xFFFFFFFFu; }

    for (int chunk = 0; chunk < NCODES / NCHUNK; ++chunk) {
        __syncthreads();
        // Stage B chunk: 64 codes x 128 halves, padded rows.
#pragma unroll
        for (int i = 0; i < 4; ++i) {
            int e   = t + i * 256;          // 0..1023
            int r   = e >> 4;               // code row in chunk
            int seg = e & 15;               // 8-half segment
            float4 v = *(const float4*)(ch + (size_t)(chunk * NCHUNK + r) * DIM + seg * 8);
            *(float4*)(bs + r * BSTRIDE + seg * 8) = v;
        }
        __syncthreads();

        f32x4 acc[2][4];
#pragma unroll
        for (int m = 0; m < 2; ++m)
#pragma unroll
            for (int j = 0; j < 4; ++j) {
                f32x4 z = {0.f, 0.f, 0.f, 0.f};
                acc[m][j] = z;
            }

#pragma unroll
        for (int ks = 0; ks < 4; ++ks) {
            half8 b0 = *(const half8*)(bs + (0 * 16 + lane15) * BSTRIDE + ks * 32 + quad * 8);
            half8 b1 = *(const half8*)(bs + (1 * 16 + lane15) * BSTRIDE + ks * 32 + quad * 8);
            half8 b2 = *(const half8*)(bs + (2 * 16 + lane15) * BSTRIDE + ks * 32 + quad * 8);
            half8 b3 = *(const half8*)(bs + (3 * 16 + lane15) * BSTRIDE + ks * 32 + quad * 8);
            acc[0][0] = __builtin_amdgcn_mfma_f32_16x16x32_f16(af[0][ks], b0, acc[0][0], 0, 0, 0);
            acc[1][0] = __builtin_amdgcn_mfma_f32_16x16x32_f16(af[1][ks], b0, acc[1][0], 0, 0, 0);
            acc[0][1] = __builtin_amdgcn_mfma_f32_16x16x32_f16(af[0][ks], b1, acc[0][1], 0, 0, 0);
            acc[1][1] = __builtin_amdgcn_mfma_f32_16x16x32_f16(af[1][ks], b1, acc[1][1], 0, 0, 0);
            acc[0][2] = __builtin_amdgcn_mfma_f32_16x16x32_f16(af[0][ks], b2, acc[0][2], 0, 0, 0);
            acc[1][2] = __builtin_amdgcn_mfma_f32_16x16x32_f16(af[1][ks], b2, acc[1][2], 0, 0, 0);
            acc[0][3] = __builtin_amdgcn_mfma_f32_16x16x32_f16(af[0][ks], b3, acc[0][3], 0, 0, 0);
            acc[1][3] = __builtin_amdgcn_mfma_f32_16x16x32_f16(af[1][ks], b3, acc[1][3], 0, 0, 0);
        }

        // Epilogue: pack scores, stream top-2 per (m,r) row state.
#pragma unroll
        for (int j = 0; j < 4; ++j) {
            int col = chunk * 64 + j * 16 + lane15;
            float cc4 = cc[col] + 4.0f;
#pragma unroll
            for (int m = 0; m < 2; ++m)
#pragma unroll
                for (int r = 0; r < 4; ++r) {
                    float s = fmaf(-2.0f, acc[m][j][r], cc4);
                    s = fmaxf(s, 0.25f);                 // keep positive (uint-monotone)
                    unsigned up = (__float_as_uint(s) & 0xFFFFFC00u) | (unsigned)col;
                    unsigned a  = p1[m][r];
                    unsigned lo = a < up ? a : up;
                    unsigned hi = a < up ? up : a;
                    p1[m][r] = lo;
                    p2[m][r] = p2[m][r] < hi ? p2[m][r] : hi;
                }
        }
    }

    // Cross-lane top-2 merge over the 16 col-lanes (bits 0..3 of lane id).
#pragma unroll
    for (int m = 0; m < 2; ++m)
#pragma unroll
        for (int r = 0; r < 4; ++r) {
            unsigned a1 = p1[m][r], a2 = p2[m][r];
#pragma unroll
            for (int mask = 1; mask <= 8; mask <<= 1) {
                unsigned b1 = (unsigned)__shfl_xor((int)a1, mask, 64);
                unsigned b2 = (unsigned)__shfl_xor((int)a2, mask, 64);
                unsigned n1 = a1 < b1 ? a1 : b1;
                unsigned hi = a1 < b1 ? b1 : a1;
                unsigned mn = a2 < b2 ? a2 : b2;
                unsigned n2 = hi < mn ? hi : mn;
                a1 = n1; a2 = n2;
            }
            if (lane15 == 0) {
                int row = rowbase + m * 16 + quad * 4 + r;
                idx[row] = (int)(a1 & 0x3FFu);
                float s1 = __uint_as_float(a1 & 0xFFFFFC00u);
                float s2 = __uint_as_float(a2 & 0xFFFFFC00u);
                if (s2 - s1 < M_TEST) {
                    int slot = atomicAdd(cnt, 1);
                    if (slot < WL_CAP) wl[slot] = row;
                }
            }
        }
}

// ---------------------------------------------------------------------------
// Phase 2: np-exact rescoring of flagged rows (verified round-3 semantics).
// One block per flagged row; thread t scores codes t, t+256, t+512, t+768.
// ---------------------------------------------------------------------------
__global__ __launch_bounds__(256) void vq_exact(const float* __restrict__ x,
                                                const float* __restrict__ cb,
                                                const float* __restrict__ cc,
                                                const int* __restrict__ cnt,
                                                const int* __restrict__ wl,
                                                int* __restrict__ idx) {
    __shared__ float xs[DIM];
    __shared__ unsigned long long red[256];
    const int t = threadIdx.x;

    int count = *cnt;
    if (count > WL_CAP) count = WL_CAP;

    for (int i = blockIdx.x; i < count; i += gridDim.x) {
        const int row = wl[i];
        __syncthreads();
        if (t < DIM) xs[t] = x[(size_t)row * DIM + t];
        __syncthreads();

        // xx: numpy pairwise sum, n=128 block, 8 accumulators (all threads).
        float r0 = sqf(xs[0]), r1 = sqf(xs[1]), r2 = sqf(xs[2]), r3 = sqf(xs[3]);
        float r4 = sqf(xs[4]), r5 = sqf(xs[5]), r6 = sqf(xs[6]), r7 = sqf(xs[7]);
#pragma unroll
        for (int k = 8; k < DIM; k += 8) {
            r0 = r0 + sqf(xs[k + 0]); r1 = r1 + sqf(xs[k + 1]);
            r2 = r2 + sqf(xs[k + 2]); r3 = r3 + sqf(xs[k + 3]);
            r4 = r4 + sqf(xs[k + 4]); r5 = r5 + sqf(xs[k + 5]);
            r6 = r6 + sqf(xs[k + 6]); r7 = r7 + sqf(xs[k + 7]);
        }
        const float xx = ((r0 + r1) + (r2 + r3)) + ((r4 + r5) + (r6 + r7));

        // sim: k-ascending sequential fmaf chain per code (BLAS order).
        float a0 = 0.f, a1 = 0.f, a2 = 0.f, a3 = 0.f;
        for (int k = 0; k < DIM; ++k) {
            const float xv = xs[k];
            const float* cr = cb + (size_t)k * NCODES + t;
            a0 = fmaf(cr[0],   xv, a0);
            a1 = fmaf(cr[256], xv, a1);
            a2 = fmaf(cr[512], xv, a2);
            a3 = fmaf(cr[768], xv, a3);
        }

        unsigned long long best = 0xFFFFFFFFFFFFFFFFull;
        float av[4] = {a0, a1, a2, a3};
#pragma unroll
        for (int c = 0; c < 4; ++c) {
            int n = t + c * 256;
            float tt = xx + cc[n];
            float d  = tt - (av[c] + av[c]);
            unsigned u = __float_as_uint(d);
            unsigned mk = (unsigned)(((int)u) >> 31);
            unsigned f = u ^ (mk | 0x80000000u);
            unsigned long long key = ((unsigned long long)f << 32) | (unsigned)n;
            best = key < best ? key : best;
        }
        red[t] = best;
        __syncthreads();
#pragma unroll
        for (int s = 128; s > 0; s >>= 1) {
            if (t < s) {
                unsigned long long o = red[t + s];
                if (o < red[t]) red[t] = o;
            }
            __syncthreads();
        }
        if (t == 0) idx[row] = (int)(red[0] & 0xFFFFFFFFull);
    }
}

// ---------------------------------------------------------------------------
// Phase 3: out = fl(x + fl(q - x)), q = codebook column idx[row].
// ---------------------------------------------------------------------------
__global__ void vq_out(const float* __restrict__ x,
                       const float* __restrict__ cbT,
                       const int* __restrict__ idx,
                       float* __restrict__ out) {
    size_t e = (size_t)blockIdx.x * 256 + threadIdx.x;   // float4 index
    int row = (int)(e >> 5);
    int k4  = (int)(e & 31);
    float4 q  = ((const float4*)cbT)[(size_t)idx[row] * 32 + k4];
    float4 xv = ((const float4*)x)[e];
    float4 o;
    o.x = xv.x + (q.x - xv.x);
    o.y = xv.y + (q.y - xv.y);
    o.z = xv.z + (q.z - xv.z);
    o.w = xv.w + (q.w - xv.w);
    ((float4*)out)[e] = o;
}

// ---------------------------------------------------------------------------
extern "C" void kernel_launch(void* const* d_in, const int* in_sizes, int n_in,
                              void* d_out, int out_size, void* d_ws, size_t ws_size,
                              hipStream_t stream) {
    const float* x  = (const float*)d_in[0];   // [131072,128] f32
    const float* cb = (const float*)d_in[1];   // [128,1024] f32
    float* out = (float*)d_out;

    // ws: cbT f32[1024*128] | ch fp16[1024*128] | cc f32[1024] | idx i32[131072]
    //     | cnt i32[16] | wl i32[WL_CAP]   (~1.4 MB total)
    char* p = (char*)d_ws;
    float*    cbT = (float*)p;               p += NCODES * DIM * sizeof(float);
    _Float16* ch  = (_Float16*)p;            p += NCODES * DIM * sizeof(_Float16);
    float*    cc  = (float*)p;               p += NCODES * sizeof(float);
    int*      idx = (int*)p;                 p += M_ROWS * sizeof(int);
    int*      cnt = (int*)p;                 p += 16 * sizeof(int);
    int*      wl  = (int*)p;

    vq_prep<<<(NCODES + 255) / 256, 256, 0, stream>>>(cb, cbT, ch, cc, cnt);
    vq_gemm<<<M_ROWS / MTILE, 256, 0, stream>>>(x, ch, cc, idx, cnt, wl);
    vq_exact<<<2048, 256, 0, stream>>>(x, cb, cc, cnt, wl, idx);
    vq_out<<<(M_ROWS * (DIM / 4)) / 256, 256, 0, stream>>>(x, cbT, idx, out);
}

// Round 5
// 251.530 us; speedup vs baseline: 5.4119x; 1.0318x over previous
//
#include <hip/hip_runtime.h>
#include <math.h>

typedef _Float16 half8 __attribute__((ext_vector_type(8)));
typedef float    f32x4 __attribute__((ext_vector_type(4)));

#define DIM     128
#define NCODES  1024
#define M_ROWS  (32*64*64)   // 131072
#define MTILE   256          // rows per block in phase 1 (4 m-frags per wave)
#define NCHUNK  64           // codes per LDS chunk in phase 1
#define BSTRIDE 136          // halves per padded LDS row
#define M_TEST  3.0e-3f      // flag margin (quantized-score gap)
#define WL_CAP  16384
#define XG      16           // flagged rows per vq_exact block
#define CSTR    132          // f32 LDS stride (528 B, 16B aligned, bank-friendly)

// fl32(v*v), immune to FMA contraction (f64 product exact, one rounding).
__device__ __forceinline__ float sqf(float v) {
    return (float)((double)v * (double)v);
}

// ---------------------------------------------------------------------------
// Prep: blocks 0..511 transpose cb->cbT (f32) and ch (fp16), one elem/thread.
// Blocks 512..515: cc[n] = np axis-0 sequential sum of rounded squares.
// ---------------------------------------------------------------------------
__global__ void vq_prep(const float* __restrict__ cb,
                        float* __restrict__ cbT,
                        _Float16* __restrict__ ch,
                        float* __restrict__ cc,
                        int* __restrict__ cnt) {
    const int b = blockIdx.x;
    if (b < 512) {
        int e = b * 256 + threadIdx.x;      // 0..131071
        int n = e & 1023, k = e >> 10;
        float v = cb[k * NCODES + n];       // coalesced in n
        cbT[n * DIM + k] = v;
        ch[n * DIM + k]  = (_Float16)v;
    } else {
        int n = (b - 512) * 256 + threadIdx.x;   // 0..1023
        float acc = 0.f;
        for (int k = 0; k < DIM; ++k)
            acc = acc + sqf(cb[k * NCODES + n]); // np axis-0 order
        cc[n] = acc;
        if (n == 0) *cnt = 0;
    }
}

// ---------------------------------------------------------------------------
// Phase 1: fp16 MFMA scoring, fused top-2 argmin. 4 waves x 64 rows = 256
// rows/block; per wave 4 m-frags x 4 n-frags, K=128 as 4 MFMA k-steps.
// Score s' = (cc[n]+4) - 2*sim, clamped >=0.25 (uint-monotone float bits).
// packed = (bits & ~0x3FF) | col. Top-2 via unsigned min/max.
// ---------------------------------------------------------------------------
__global__ __launch_bounds__(256, 2) void vq_gemm(const float* __restrict__ x,
                                                  const _Float16* __restrict__ ch,
                                                  const float* __restrict__ cc,
                                                  int* __restrict__ idx,
                                                  int* __restrict__ cnt,
                                                  int* __restrict__ wl) {
    __shared__ _Float16 bs[NCHUNK * BSTRIDE];
    __shared__ float ccS[NCHUNK];

    const int t      = threadIdx.x;
    const int w      = t >> 6;
    const int L      = t & 63;
    const int lane15 = L & 15;
    const int quad   = L >> 4;
    const int rowbase = blockIdx.x * MTILE + w * 64;

    // A fragments from global x (f32 -> fp16), persistent across chunks.
    half8 af[4][4];
#pragma unroll
    for (int m = 0; m < 4; ++m) {
#pragma unroll
        for (int ks = 0; ks < 4; ++ks) {
            const float* src = x + (size_t)(rowbase + m * 16 + lane15) * DIM
                                 + ks * 32 + quad * 8;
            float4 f0 = *(const float4*)src;
            float4 f1 = *(const float4*)(src + 4);
            half8 h;
            h[0] = (_Float16)f0.x; h[1] = (_Float16)f0.y;
            h[2] = (_Float16)f0.z; h[3] = (_Float16)f0.w;
            h[4] = (_Float16)f1.x; h[5] = (_Float16)f1.y;
            h[6] = (_Float16)f1.z; h[7] = (_Float16)f1.w;
            af[m][ks] = h;
        }
    }

    unsigned p1[4][4], p2[4][4];
#pragma unroll
    for (int m = 0; m < 4; ++m)
#pragma unroll
        for (int r = 0; r < 4; ++r) { p1[m][r] = 0xFFFFFFFFu; p2[m][r] = 0xFFFFFFFFu; }

    for (int chunk = 0; chunk < NCODES / NCHUNK; ++chunk) {
        __syncthreads();
#pragma unroll
        for (int i = 0; i < 4; ++i) {
            int e   = t + i * 256;          // 0..1023
            int r   = e >> 4;
            int seg = e & 15;
            float4 v = *(const float4*)(ch + (size_t)(chunk * NCHUNK + r) * DIM + seg * 8);
            *(float4*)(bs + r * BSTRIDE + seg * 8) = v;
        }
        if (t < NCHUNK) ccS[t] = cc[chunk * NCHUNK + t];
        __syncthreads();

        f32x4 acc[4][4];
#pragma unroll
        for (int m = 0; m < 4; ++m)
#pragma unroll
            for (int j = 0; j < 4; ++j) {
                f32x4 z = {0.f, 0.f, 0.f, 0.f};
                acc[m][j] = z;
            }

#pragma unroll
        for (int ks = 0; ks < 4; ++ks) {
            half8 bf[4];
#pragma unroll
            for (int j = 0; j < 4; ++j)
                bf[j] = *(const half8*)(bs + (j * 16 + lane15) * BSTRIDE + ks * 32 + quad * 8);
#pragma unroll
            for (int j = 0; j < 4; ++j)
#pragma unroll
                for (int m = 0; m < 4; ++m)
                    acc[m][j] = __builtin_amdgcn_mfma_f32_16x16x32_f16(af[m][ks], bf[j], acc[m][j], 0, 0, 0);
        }

#pragma unroll
        for (int j = 0; j < 4; ++j) {
            int col = chunk * NCHUNK + j * 16 + lane15;
            float cc4 = ccS[j * 16 + lane15] + 4.0f;
#pragma unroll
            for (int m = 0; m < 4; ++m)
#pragma unroll
                for (int r = 0; r < 4; ++r) {
                    float s = fmaf(-2.0f, acc[m][j][r], cc4);
                    s = fmaxf(s, 0.25f);
                    unsigned up = (__float_as_uint(s) & 0xFFFFFC00u) | (unsigned)col;
                    unsigned a  = p1[m][r];
                    unsigned lo = a < up ? a : up;
                    unsigned hi = a < up ? up : a;
                    p1[m][r] = lo;
                    p2[m][r] = p2[m][r] < hi ? p2[m][r] : hi;
                }
        }
    }

    // Cross-lane top-2 merge over the 16 col-lanes.
#pragma unroll
    for (int m = 0; m < 4; ++m)
#pragma unroll
        for (int r = 0; r < 4; ++r) {
            unsigned a1 = p1[m][r], a2 = p2[m][r];
#pragma unroll
            for (int mask = 1; mask <= 8; mask <<= 1) {
                unsigned b1 = (unsigned)__shfl_xor((int)a1, mask, 64);
                unsigned b2 = (unsigned)__shfl_xor((int)a2, mask, 64);
                unsigned n1 = a1 < b1 ? a1 : b1;
                unsigned hi = a1 < b1 ? b1 : a1;
                unsigned mn = a2 < b2 ? a2 : b2;
                unsigned n2 = hi < mn ? hi : mn;
                a1 = n1; a2 = n2;
            }
            if (lane15 == 0) {
                int row = rowbase + m * 16 + quad * 4 + r;
                idx[row] = (int)(a1 & 0x3FFu);
                float s1 = __uint_as_float(a1 & 0xFFFFFC00u);
                float s2 = __uint_as_float(a2 & 0xFFFFFC00u);
                if (s2 - s1 < M_TEST) {
                    int slot = atomicAdd(cnt, 1);
                    if (slot < WL_CAP) wl[slot] = row;
                }
            }
        }
}

// ---------------------------------------------------------------------------
// Phase 2 v2: np-exact rescoring, 16 flagged rows per block, codebook chunks
// staged in LDS (read once per block, not once per row). Thread (r,q) runs
// 4 sequential k-chains (codes q,q+16,q+32,q+48 of each 64-code chunk) —
// identical per-(row,code) np semantics as the verified round-3/4 kernels.
// ---------------------------------------------------------------------------
__global__ __launch_bounds__(256) void vq_exact(const float* __restrict__ x,
                                                const float* __restrict__ cbT,
                                                const float* __restrict__ cc,
                                                const int* __restrict__ cnt,
                                                const int* __restrict__ wl,
                                                int* __restrict__ idx) {
    __shared__ float xsS[XG * CSTR];                 // 16 rows
    __shared__ float cbS[64 * CSTR];                 // 64-code chunk
    __shared__ unsigned long long red[XG][17];

    const int t = threadIdx.x;
    const int r = t >> 4;      // row slot 0..15
    const int q = t & 15;      // code residue 0..15

    int count = *cnt;
    if (count > WL_CAP) count = WL_CAP;
    const int nblk = (count + XG - 1) / XG;

    for (int b = blockIdx.x; b < nblk; b += gridDim.x) {
        int slot = b * XG + r;
        int row  = wl[slot < count ? slot : count - 1];  // clamp: dup rows benign

        __syncthreads();   // previous iteration's readers done
        // Stage 16 x-rows (coalesced 256B runs).
#pragma unroll
        for (int j = 0; j < 8; ++j) {
            int e  = t + 256 * j;     // 0..2047
            int rr = e >> 7, kk = e & 127;
            int sl = b * XG + rr;
            int rw = wl[sl < count ? sl : count - 1];
            xsS[rr * CSTR + kk] = x[(size_t)rw * DIM + kk];
        }
        __syncthreads();

        // xx: numpy pairwise sum, n=128 block, 8 accumulators (verified form).
        const float* xs = &xsS[r * CSTR];
        float r0 = sqf(xs[0]), r1 = sqf(xs[1]), r2 = sqf(xs[2]), r3 = sqf(xs[3]);
        float r4 = sqf(xs[4]), r5 = sqf(xs[5]), r6 = sqf(xs[6]), r7 = sqf(xs[7]);
#pragma unroll
        for (int k = 8; k < DIM; k += 8) {
            r0 = r0 + sqf(xs[k + 0]); r1 = r1 + sqf(xs[k + 1]);
            r2 = r2 + sqf(xs[k + 2]); r3 = r3 + sqf(xs[k + 3]);
            r4 = r4 + sqf(xs[k + 4]); r5 = r5 + sqf(xs[k + 5]);
            r6 = r6 + sqf(xs[k + 6]); r7 = r7 + sqf(xs[k + 7]);
        }
        const float xx = ((r0 + r1) + (r2 + r3)) + ((r4 + r5) + (r6 + r7));

        unsigned long long best = 0xFFFFFFFFFFFFFFFFull;

        for (int chunk = 0; chunk < NCODES / 64; ++chunk) {
            __syncthreads();
            // Stage 64 codes (f32, from cbT[n][k]).
#pragma unroll
            for (int j = 0; j < 8; ++j) {
                int e  = t + 256 * j;         // float4 index 0..2047
                int ci = e >> 5, k4 = e & 31;
                float4 v = ((const float4*)cbT)[(size_t)(chunk * 64 + ci) * 32 + k4];
                *(float4*)&cbS[ci * CSTR + k4 * 4] = v;
            }
            __syncthreads();

            // 4 sequential k-ascending fmaf chains (np/BLAS order per code).
            float a0 = 0.f, a1 = 0.f, a2 = 0.f, a3 = 0.f;
#pragma unroll
            for (int k4 = 0; k4 < 32; ++k4) {
                float4 xv = *(const float4*)&xsS[r * CSTR + k4 * 4];
                float4 c0 = *(const float4*)&cbS[(q +  0) * CSTR + k4 * 4];
                float4 c1 = *(const float4*)&cbS[(q + 16) * CSTR + k4 * 4];
                float4 c2 = *(const float4*)&cbS[(q + 32) * CSTR + k4 * 4];
                float4 c3 = *(const float4*)&cbS[(q + 48) * CSTR + k4 * 4];
                a0 = fmaf(c0.x, xv.x, a0); a0 = fmaf(c0.y, xv.y, a0);
                a0 = fmaf(c0.z, xv.z, a0); a0 = fmaf(c0.w, xv.w, a0);
                a1 = fmaf(c1.x, xv.x, a1); a1 = fmaf(c1.y, xv.y, a1);
                a1 = fmaf(c1.z, xv.z, a1); a1 = fmaf(c1.w, xv.w, a1);
                a2 = fmaf(c2.x, xv.x, a2); a2 = fmaf(c2.y, xv.y, a2);
                a2 = fmaf(c2.z, xv.z, a2); a2 = fmaf(c2.w, xv.w, a2);
                a3 = fmaf(c3.x, xv.x, a3); a3 = fmaf(c3.y, xv.y, a3);
                a3 = fmaf(c3.z, xv.z, a3); a3 = fmaf(c3.w, xv.w, a3);
            }

            float av[4] = {a0, a1, a2, a3};
#pragma unroll
            for (int j = 0; j < 4; ++j) {
                int n = chunk * 64 + q + 16 * j;
                float tt = xx + cc[n];
                float d  = tt - (av[j] + av[j]);
                unsigned u  = __float_as_uint(d);
                unsigned mk = (unsigned)(((int)u) >> 31);
                unsigned f  = u ^ (mk | 0x80000000u);
                unsigned long long key = ((unsigned long long)f << 32) | (unsigned)n;
                best = key < best ? key : best;
            }
        }

        red[r][q] = best;
        __syncthreads();
        if (q == 0) {
            unsigned long long m = red[r][0];
#pragma unroll
            for (int i = 1; i < 16; ++i) {
                unsigned long long o = red[r][i];
                m = o < m ? o : m;
            }
            idx[row] = (int)(m & 0xFFFFFFFFull);
        }
    }
}

// ---------------------------------------------------------------------------
// Phase 3: out = q (codebook column idx[row]); |q - (x + fl(q-x))| <= 4e-7,
// well under the 1e-3 threshold, and skips the 64 MB x read.
// ---------------------------------------------------------------------------
__global__ void vq_out(const float* __restrict__ cbT,
                       const int* __restrict__ idx,
                       float* __restrict__ out) {
    size_t e = (size_t)blockIdx.x * 256 + threadIdx.x;   // float4 index
    int row = (int)(e >> 5);
    int k4  = (int)(e & 31);
    ((float4*)out)[e] = ((const float4*)cbT)[(size_t)idx[row] * 32 + k4];
}

// ---------------------------------------------------------------------------
extern "C" void kernel_launch(void* const* d_in, const int* in_sizes, int n_in,
                              void* d_out, int out_size, void* d_ws, size_t ws_size,
                              hipStream_t stream) {
    const float* x  = (const float*)d_in[0];   // [131072,128] f32
    const float* cb = (const float*)d_in[1];   // [128,1024] f32
    float* out = (float*)d_out;

    char* p = (char*)d_ws;
    float*    cbT = (float*)p;               p += NCODES * DIM * sizeof(float);
    _Float16* ch  = (_Float16*)p;            p += NCODES * DIM * sizeof(_Float16);
    float*    cc  = (float*)p;               p += NCODES * sizeof(float);
    int*      idx = (int*)p;                 p += M_ROWS * sizeof(int);
    int*      cnt = (int*)p;                 p += 16 * sizeof(int);
    int*      wl  = (int*)p;

    vq_prep<<<516, 256, 0, stream>>>(cb, cbT, ch, cc, cnt);
    vq_gemm<<<M_ROWS / MTILE, 256, 0, stream>>>(x, ch, cc, idx, cnt, wl);
    vq_exact<<<512, 256, 0, stream>>>(x, cbT, cc, cnt, wl, idx);
    vq_out<<<(M_ROWS * (DIM / 4)) / 256, 256, 0, stream>>>(cbT, idx, out);
}